// Round 11
// baseline (69.092 us; speedup 1.0000x reference)
//
#include <hip/hip_runtime.h>
#include <hip/hip_bf16.h>

typedef __bf16 bf16x8 __attribute__((ext_vector_type(8)));
typedef float f32x16 __attribute__((ext_vector_type(16)));

#define B_N 2048
#define O_N 2048
#define K_TRI 2080
#define K_TOT 2304
#define K_STEPS 36
#define ROWB (K_TOT * 2)          // 4608 bytes per S/P row

__device__ __forceinline__ void gld16(const void* g, void* l) {
    __builtin_amdgcn_global_load_lds(
        (const __attribute__((address_space(1))) void*)g,
        (__attribute__((address_space(3))) void*)l,
        16, 0, 0);
}

// ---------------------------------------------------------------------------
// prep2 (identical math to R10, proven absmax 1.22e-4):
//   S rows (o) / P rows (b), row-major, K_TOT=2304 cols:
//   [0,2080) tri-packed quad | [2080,2208) c/x hi-lo cross | [2272,2274) k|1
// ---------------------------------------------------------------------------
__global__ __launch_bounds__(256) void rbf_prep2(
    const float* __restrict__ inv, const float* __restrict__ means,
    const float* __restrict__ x, __bf16* __restrict__ S, __bf16* __restrict__ P)
{
    __shared__ float s[64 * 65];
    __shared__ float mld[64];
    __shared__ float uw[128];
    __shared__ unsigned short ptab[K_TRI];

    const int t = threadIdx.x;
    {
        int base = 0;
#pragma unroll 1
        for (int i = 0; i < 64; ++i) {
            if (t < 64 - i) ptab[base + t] = (unsigned short)((i << 8) | (i + t));
            base += 64 - i;
        }
    }

    if ((int)blockIdx.x < O_N) {
        const int o = blockIdx.x;
        const float4* src = (const float4*)(inv + (size_t)o * 4096);
#pragma unroll
        for (int k = 0; k < 4; ++k) {
            const int idx = k * 256 + t;
            const float4 v = src[idx];
            const int i = idx >> 4;
            const int j0 = (idx & 15) * 4;
            s[i * 65 + j0 + 0] = v.x * v.x;
            s[i * 65 + j0 + 1] = v.y * v.y;
            s[i * 65 + j0 + 2] = v.z * v.z;
            s[i * 65 + j0 + 3] = v.w * v.w;
        }
        if (t < 64) mld[t] = means[(size_t)t * O_N + o];
        __syncthreads();
        if (t < 64) {
            float u = 0.f;
#pragma unroll
            for (int i = 0; i < 64; ++i) u = fmaf(s[i * 65 + t], mld[i], u);
            uw[t] = u;
        } else if (t < 128) {
            const int j = t - 64;
            float w = 0.f;
#pragma unroll
            for (int i = 0; i < 64; ++i) w = fmaf(s[j * 65 + i], mld[i], w);
            uw[64 + j] = w;
        }
        __syncthreads();
        __bf16* Srow = S + (size_t)o * K_TOT;
#pragma unroll 1
        for (int p = t; p < K_TRI; p += 256) {
            const int ij = ptab[p];
            const int i = ij >> 8, j = ij & 255;
            const float v = (i == j) ? s[i * 65 + i]
                                     : (s[i * 65 + j] + s[j * 65 + i]);
            Srow[p] = (__bf16)v;
        }
        if (t < 64) {
            const float c = -(uw[t] + uw[64 + t]);
            const __bf16 hi = (__bf16)c;
            const __bf16 lo = (__bf16)(c - (float)hi);
            Srow[K_TRI + t] = hi;
            Srow[K_TRI + 64 + t] = hi;
            Srow[K_TRI + 128 + t] = lo;
        }
        if (t == 0) {
            float kk = 0.f;
#pragma unroll
            for (int j = 0; j < 64; ++j) kk = fmaf(uw[j], mld[j], kk);
            const __bf16 khi = (__bf16)kk;
            const __bf16 klo = (__bf16)(kk - (float)khi);
            Srow[2272] = khi;
            Srow[2273] = klo;
        }
        if (t < K_TOT - 2274) Srow[2274 + t] = (__bf16)0.f;
    } else {
        const int b = (int)blockIdx.x - O_N;
        if (t < 64) mld[t] = x[(size_t)b * 64 + t];
        __syncthreads();
        __bf16* Prow = P + (size_t)b * K_TOT;
#pragma unroll 1
        for (int p = t; p < K_TRI; p += 256) {
            const int ij = ptab[p];
            Prow[p] = (__bf16)(mld[ij >> 8] * mld[ij & 255]);
        }
        if (t < 64) {
            const float v = mld[t];
            const __bf16 hi = (__bf16)v;
            Prow[K_TRI + t] = hi;
            Prow[K_TRI + 64 + t] = (__bf16)(v - (float)hi);
            Prow[K_TRI + 128 + t] = hi;
        }
        if (t == 0) {
            Prow[2272] = (__bf16)1.f;
            Prow[2273] = (__bf16)1.f;
        }
        if (t < K_TOT - 2274) Prow[2274 + t] = (__bf16)0.f;
    }
}

// ---------------------------------------------------------------------------
// GEMM: C[128b x 128o] per block; grid 256 = 1 block/CU; 4 waves, each a
// 64x64 tile (acc 2x2 f32x16). LDS per K=64 step: A[ks8][row128][16B] +
// B[ks8][col128][16B] (32KB) -> fragment reads are dense stride-16 (lane
// l vs l+32 = different 2048-plane, 2-way free). Staging: 8 gld16/thread,
// per-lane scattered global src (row-major, +128B/step), linear LDS dest.
// 4 buffers, 2-step prefetch, raw s_barrier + counted vmcnt (never 0).
// C-layout (32x32): col = lane&31, row = (r&3)+8*(r>>2)+4*(lane>>5).
// ---------------------------------------------------------------------------
__global__ __launch_bounds__(256, 1) void rbf_gemm(
    const __bf16* __restrict__ P, const __bf16* __restrict__ S,
    float* __restrict__ out)
{
    __shared__ __align__(16) char sAB[4][32768];

    const int tid = threadIdx.x;
    const int lane = tid & 63;
    const int w = tid >> 6;
    const int wr = w >> 1, wc = w & 1;
    const int cl = lane & 31;
    const int h = lane >> 5;

    // grid 256 = 8 XCD x (2 o-blk x 16 b-blk); S slice 1.2MB per-XCD L2
    const int wg = (int)blockIdx.x;
    const int xcd = wg & 7;
    const int loc = wg >> 3;               // 0..31
    const int oBase = (xcd * 2 + (loc & 1)) * 128;
    const int bBase = (loc >> 1) * 128;

    // staging map: round r, thread t -> LDS byte Ld = r*4096 + t*16
    //   Ld < 16384: A-half: ks = Ld>>11, row = (Ld>>4)&127  (P rows)
    //   else      : B-half: same with S rows
    const char* gsrc[8];
    int ldst[8];
#pragma unroll
    for (int r = 0; r < 8; ++r) {
        const int Ld = r * 4096 + tid * 16;
        ldst[r] = Ld;
        const int Lo = Ld & 16383;
        const int ks = Lo >> 11;
        const int row = (Lo >> 4) & 127;
        gsrc[r] = ((Ld >> 14) ? (const char*)S + (size_t)(oBase + row) * ROWB
                              : (const char*)P + (size_t)(bBase + row) * ROWB)
                  + ks * 16;
    }

#define RBF_STAGE(ST) do {                                                    \
    const size_t go_ = (size_t)(ST) * 128;                                    \
    char* d_ = &sAB[(ST) & 3][0];                                             \
    _Pragma("unroll")                                                         \
    for (int r_ = 0; r_ < 8; ++r_)                                            \
        gld16(gsrc[r_] + go_, d_ + ldst[r_]);                                 \
} while (0)

    RBF_STAGE(0);
    RBF_STAGE(1);

    const f32x16 zz = {0.f,0.f,0.f,0.f,0.f,0.f,0.f,0.f,
                       0.f,0.f,0.f,0.f,0.f,0.f,0.f,0.f};
    f32x16 acc00 = zz, acc01 = zz, acc10 = zz, acc11 = zz;

    const int aoff = (wr * 64 + cl) * 16;             // + i*512
    const int boff = 16384 + (wc * 64 + cl) * 16;     // + j*512

#pragma unroll 1
    for (int st = 0; st < K_STEPS; ++st) {
        if (st + 2 < K_STEPS) {
            RBF_STAGE(st + 2);
            asm volatile("s_waitcnt vmcnt(16)" ::: "memory");
        } else if (st + 1 < K_STEPS) {
            asm volatile("s_waitcnt vmcnt(8)" ::: "memory");
        } else {
            asm volatile("s_waitcnt vmcnt(0)" ::: "memory");
        }
        __builtin_amdgcn_s_barrier();
        const char* bp = &sAB[st & 3][0];

        __builtin_amdgcn_s_setprio(1);
#pragma unroll
        for (int sl = 0; sl < 4; ++sl) {
            const int kso = (sl * 2 + h) * 2048;
            const bf16x8 a0 = *(const bf16x8*)(bp + kso + aoff);
            const bf16x8 a1 = *(const bf16x8*)(bp + kso + aoff + 512);
            const bf16x8 b0 = *(const bf16x8*)(bp + kso + boff);
            const bf16x8 b1 = *(const bf16x8*)(bp + kso + boff + 512);
            acc00 = __builtin_amdgcn_mfma_f32_32x32x16_bf16(a0, b0, acc00, 0, 0, 0);
            acc01 = __builtin_amdgcn_mfma_f32_32x32x16_bf16(a0, b1, acc01, 0, 0, 0);
            acc10 = __builtin_amdgcn_mfma_f32_32x32x16_bf16(a1, b0, acc10, 0, 0, 0);
            acc11 = __builtin_amdgcn_mfma_f32_32x32x16_bf16(a1, b1, acc11, 0, 0, 0);
        }
        __builtin_amdgcn_s_setprio(0);
    }
#undef RBF_STAGE

    // epilogue: out[b][o] = exp(-q/2)
#pragma unroll
    for (int r = 0; r < 16; ++r) {
        const int row32 = (r & 3) + 8 * (r >> 2) + 4 * h;
        const size_t r0 = (size_t)(bBase + wr * 64 + row32) * O_N;
        const size_t r1 = (size_t)(bBase + wr * 64 + 32 + row32) * O_N;
        const int c0 = oBase + wc * 64 + cl;
        const int c1 = oBase + wc * 64 + 32 + cl;
        out[r0 + c0] = exp2f(acc00[r] * -0.72134752044448170368f);
        out[r0 + c1] = exp2f(acc01[r] * -0.72134752044448170368f);
        out[r1 + c0] = exp2f(acc10[r] * -0.72134752044448170368f);
        out[r1 + c1] = exp2f(acc11[r] * -0.72134752044448170368f);
    }
}

extern "C" void kernel_launch(void* const* d_in, const int* in_sizes, int n_in,
                              void* d_out, int out_size, void* d_ws, size_t ws_size,
                              hipStream_t stream)
{
    const float* x = (const float*)d_in[0];
    const float* means = (const float*)d_in[1];
    const float* inv = (const float*)d_in[2];
    float* out = (float*)d_out;

    // workspace: S 9.44 MB | P 9.44 MB
    __bf16* S = (__bf16*)d_ws;
    __bf16* P = (__bf16*)((char*)d_ws + (size_t)O_N * K_TOT * sizeof(__bf16));

    rbf_prep2<<<dim3(2 * O_N), dim3(256), 0, stream>>>(inv, means, x, S, P);
    rbf_gemm<<<dim3(256), dim3(256), 0, stream>>>(P, S, out);

    (void)in_sizes; (void)n_in; (void)out_size; (void)ws_size;
}

// Round 12
// 63.515 us; speedup vs baseline: 1.0878x; 1.0878x over previous
//
#include <hip/hip_runtime.h>
#include <hip/hip_bf16.h>

typedef __bf16 bf16x8 __attribute__((ext_vector_type(8)));
typedef float f32x16 __attribute__((ext_vector_type(16)));

#define B_N 2048
#define O_N 2048
#define K_TRI 2080
#define K_TOT 2304
#define K_STEPS 36
#define CHUNKS 288                 // K_TOT/8 16B-chunks per row

__device__ __forceinline__ void gld16(const void* g, void* l) {
    __builtin_amdgcn_global_load_lds(
        (const __attribute__((address_space(1))) void*)g,
        (__attribute__((address_space(3))) void*)l,
        16, 0, 0);
}

// ---------------------------------------------------------------------------
// prep3: builds S/P directly in the GEMM's tiled layout
//   T[(st*8+ks)*2048 + row][16B]  i.e. chunk c8 = col/8 -> element base
//   (c8*2048 + row)*8.  Each block computes 8 rows (S: o, P: b) into an LDS
//   out-buffer, then writes full 128B lines (8 rows x 16B per chunk).
// Column semantics (col c, same math as R10/R11, absmax-proven):
//   [0,2080)  tri-pack: S: A_ii / A_ij+A_ji ; P: x_i*x_j
//   [2080,2144) S: c_hi  P: x_hi     [2144,2208) S: c_hi  P: x_lo
//   [2208,2272) S: c_lo  P: x_hi     2272/2273: S: k_hi/k_lo  P: 1/1
//   [2274,2304) zeros
// ---------------------------------------------------------------------------
__global__ __launch_bounds__(256) void rbf_prep3(
    const float* __restrict__ inv, const float* __restrict__ means,
    const float* __restrict__ x, __bf16* __restrict__ St, __bf16* __restrict__ Pt)
{
    __shared__ float s[64 * 65];
    __shared__ float mld[64];
    __shared__ float uw[128];
    __shared__ unsigned short ptab[K_TRI];
    __shared__ unsigned short obuf[CHUNKS * 64];   // [chunk][r8][8]

    const int t = threadIdx.x;
    {
        int base = 0;
#pragma unroll 1
        for (int i = 0; i < 64; ++i) {
            if (t < 64 - i) ptab[base + t] = (unsigned short)((i << 8) | (i + t));
            base += 64 - i;
        }
    }
    const bool isS = (int)blockIdx.x < 256;
    const int g0 = (isS ? (int)blockIdx.x : (int)blockIdx.x - 256) * 8;

    if (isS) {
#pragma unroll 1
        for (int r8 = 0; r8 < 8; ++r8) {
            const int o = g0 + r8;
            __syncthreads();                       // s[]/uw reuse barrier
            const float4* src = (const float4*)(inv + (size_t)o * 4096);
#pragma unroll
            for (int k = 0; k < 4; ++k) {
                const int idx = k * 256 + t;
                const float4 v = src[idx];
                const int i = idx >> 4;
                const int j0 = (idx & 15) * 4;
                s[i * 65 + j0 + 0] = v.x * v.x;
                s[i * 65 + j0 + 1] = v.y * v.y;
                s[i * 65 + j0 + 2] = v.z * v.z;
                s[i * 65 + j0 + 3] = v.w * v.w;
            }
            if (t < 64) mld[t] = means[(size_t)t * O_N + o];
            __syncthreads();
            if (t < 64) {                          // u_j = col-dot
                float u = 0.f;
#pragma unroll
                for (int i = 0; i < 64; ++i) u = fmaf(s[i * 65 + t], mld[i], u);
                uw[t] = u;
            } else if (t < 128) {                  // w_j = row-dot
                const int j = t - 64;
                float w = 0.f;
#pragma unroll
                for (int i = 0; i < 64; ++i) w = fmaf(s[j * 65 + i], mld[i], w);
                uw[64 + j] = w;
            }
            __syncthreads();
#pragma unroll 1
            for (int c = t; c < K_TOT; c += 256) {
                float v;
                if (c < K_TRI) {
                    const int ij = ptab[c];
                    const int i = ij >> 8, j = ij & 255;
                    v = (i == j) ? s[i * 65 + i] : (s[i * 65 + j] + s[j * 65 + i]);
                } else if (c < 2272) {
                    const int j = (c - K_TRI) & 63;
                    const float cv = -(uw[j] + uw[64 + j]);
                    const __bf16 hi = (__bf16)cv;
                    v = (c < 2208) ? (float)hi : (cv - (float)hi);
                } else if (c < 2274) {
                    float kk = 0.f;
#pragma unroll
                    for (int j = 0; j < 64; ++j) kk = fmaf(uw[j], mld[j], kk);
                    const __bf16 khi = (__bf16)kk;
                    v = (c == 2272) ? (float)khi : (kk - (float)khi);
                } else v = 0.f;
                obuf[(c >> 3) * 64 + r8 * 8 + (c & 7)] =
                    __builtin_bit_cast(unsigned short, (__bf16)v);
            }
        }
    } else {
        // xb rows in s[] (stride 65)
#pragma unroll
        for (int q = 0; q < 2; ++q) {
            const int idx = q * 256 + t;
            s[(idx >> 6) * 65 + (idx & 63)] = x[(size_t)(g0 + (idx >> 6)) * 64 + (idx & 63)];
        }
        __syncthreads();
#pragma unroll 1
        for (int r8 = 0; r8 < 8; ++r8) {
            const float* xr = &s[r8 * 65];
#pragma unroll 1
            for (int c = t; c < K_TOT; c += 256) {
                float v;
                if (c < K_TRI) {
                    const int ij = ptab[c];
                    v = xr[ij >> 8] * xr[ij & 255];
                } else if (c < 2272) {
                    const float xv = xr[(c - K_TRI) & 63];
                    const __bf16 hi = (__bf16)xv;
                    v = (c < 2144) ? (float)hi
                      : (c < 2208) ? (xv - (float)hi) : (float)hi;
                } else if (c < 2274) v = 1.f;
                else v = 0.f;
                obuf[(c >> 3) * 64 + r8 * 8 + (c & 7)] =
                    __builtin_bit_cast(unsigned short, (__bf16)v);
            }
        }
    }
    __syncthreads();
    __bf16* dst = isS ? St : Pt;
#pragma unroll 1
    for (int idx = t; idx < CHUNKS * 8; idx += 256) {
        const int chunk = idx >> 3, r8 = idx & 7;
        const bf16x8 v = *(const bf16x8*)&obuf[chunk * 64 + r8 * 8];
        *(bf16x8*)(dst + ((size_t)chunk * 2048 + g0 + r8) * 8) = v;
    }
}

// ---------------------------------------------------------------------------
// GEMM (R11 body, 0 bank conflicts proven): C[128b x 128o]/block, grid 256 =
// 1 block/CU, 4 waves x 64x64. NOW with tiled global S/P: every staging round
// is a contiguous 2KB segment -> full-line coalesced gld16 (was 64-line
// gather). 4 buffers, 2-step prefetch, counted vmcnt, setprio.
// C-layout (32x32): col = lane&31, row = (r&3)+8*(r>>2)+4*(lane>>5).
// ---------------------------------------------------------------------------
__global__ __launch_bounds__(256, 1) void rbf_gemm(
    const __bf16* __restrict__ P, const __bf16* __restrict__ S,
    float* __restrict__ out)
{
    __shared__ __align__(16) char sAB[4][32768];

    const int tid = threadIdx.x;
    const int lane = tid & 63;
    const int w = tid >> 6;
    const int wr = w >> 1, wc = w & 1;
    const int cl = lane & 31;
    const int h = lane >> 5;

    const int wg = (int)blockIdx.x;
    const int xcd = wg & 7;
    const int loc = wg >> 3;               // 0..31
    const int oBase = (xcd * 2 + (loc & 1)) * 128;
    const int bBase = (loc >> 1) * 128;

    // staging: round r, thread t -> LDS byte r*4096 + t*16;
    // src chunk ks = (r&3)*2 + (t>>7), row = t&127, P-half for r<4 else S.
    const char* gsrc[8];
#pragma unroll
    for (int r = 0; r < 8; ++r) {
        const int ks = (r & 3) * 2 + (tid >> 7);
        const int row = tid & 127;
        gsrc[r] = (r < 4)
            ? (const char*)P + ((size_t)ks * 2048 + bBase + row) * 16
            : (const char*)S + ((size_t)ks * 2048 + oBase + row) * 16;
    }

#define RBF_STAGE(ST) do {                                                    \
    const size_t go_ = (size_t)(ST) * 262144;   /* 8 chunks * 2048 * 16B */   \
    char* d_ = &sAB[(ST) & 3][0];                                             \
    _Pragma("unroll")                                                         \
    for (int r_ = 0; r_ < 8; ++r_)                                            \
        gld16(gsrc[r_] + go_, d_ + r_ * 4096 + tid * 16);                     \
} while (0)

    RBF_STAGE(0);
    RBF_STAGE(1);

    const f32x16 zz = {0.f,0.f,0.f,0.f,0.f,0.f,0.f,0.f,
                       0.f,0.f,0.f,0.f,0.f,0.f,0.f,0.f};
    f32x16 acc00 = zz, acc01 = zz, acc10 = zz, acc11 = zz;

    const int aoff = (wr * 64 + cl) * 16;             // + i*512
    const int boff = 16384 + (wc * 64 + cl) * 16;     // + j*512

#pragma unroll 1
    for (int st = 0; st < K_STEPS; ++st) {
        if (st + 2 < K_STEPS) {
            RBF_STAGE(st + 2);
            asm volatile("s_waitcnt vmcnt(16)" ::: "memory");
        } else if (st + 1 < K_STEPS) {
            asm volatile("s_waitcnt vmcnt(8)" ::: "memory");
        } else {
            asm volatile("s_waitcnt vmcnt(0)" ::: "memory");
        }
        __builtin_amdgcn_s_barrier();
        const char* bp = &sAB[st & 3][0];

        __builtin_amdgcn_s_setprio(1);
#pragma unroll
        for (int sl = 0; sl < 4; ++sl) {
            const int kso = (sl * 2 + h) * 2048;
            const bf16x8 a0 = *(const bf16x8*)(bp + kso + aoff);
            const bf16x8 a1 = *(const bf16x8*)(bp + kso + aoff + 512);
            const bf16x8 b0 = *(const bf16x8*)(bp + kso + boff);
            const bf16x8 b1 = *(const bf16x8*)(bp + kso + boff + 512);
            acc00 = __builtin_amdgcn_mfma_f32_32x32x16_bf16(a0, b0, acc00, 0, 0, 0);
            acc01 = __builtin_amdgcn_mfma_f32_32x32x16_bf16(a0, b1, acc01, 0, 0, 0);
            acc10 = __builtin_amdgcn_mfma_f32_32x32x16_bf16(a1, b0, acc10, 0, 0, 0);
            acc11 = __builtin_amdgcn_mfma_f32_32x32x16_bf16(a1, b1, acc11, 0, 0, 0);
        }
        __builtin_amdgcn_s_setprio(0);
    }
#undef RBF_STAGE

#pragma unroll
    for (int r = 0; r < 16; ++r) {
        const int row32 = (r & 3) + 8 * (r >> 2) + 4 * h;
        const size_t r0 = (size_t)(bBase + wr * 64 + row32) * O_N;
        const size_t r1 = (size_t)(bBase + wr * 64 + 32 + row32) * O_N;
        const int c0 = oBase + wc * 64 + cl;
        const int c1 = oBase + wc * 64 + 32 + cl;
        out[r0 + c0] = exp2f(acc00[r] * -0.72134752044448170368f);
        out[r0 + c1] = exp2f(acc01[r] * -0.72134752044448170368f);
        out[r1 + c0] = exp2f(acc10[r] * -0.72134752044448170368f);
        out[r1 + c1] = exp2f(acc11[r] * -0.72134752044448170368f);
    }
}

extern "C" void kernel_launch(void* const* d_in, const int* in_sizes, int n_in,
                              void* d_out, int out_size, void* d_ws, size_t ws_size,
                              hipStream_t stream)
{
    const float* x = (const float*)d_in[0];
    const float* means = (const float*)d_in[1];
    const float* inv = (const float*)d_in[2];
    float* out = (float*)d_out;

    // workspace: St 9.44 MB | Pt 9.44 MB (tiled layouts)
    __bf16* St = (__bf16*)d_ws;
    __bf16* Pt = (__bf16*)((char*)d_ws + (size_t)K_STEPS * 8 * 2048 * 16);

    rbf_prep3<<<dim3(512), dim3(256), 0, stream>>>(inv, means, x, St, Pt);
    rbf_gemm<<<dim3(256), dim3(256), 0, stream>>>(Pt, St, out);

    (void)in_sizes; (void)n_in; (void)out_size; (void)ws_size;
}